// Round 9
// baseline (169.886 us; speedup 1.0000x reference)
//
#include <hip/hip_runtime.h>

// SSIM loss, fused separable Gaussian (11x11, sigma=1.5) over [32,3,512,512] f32.
// R9 = R8 with two targeted fixes:
//  (1) asm-liveness anchor: one asm volatile consuming all 28 loaded values as
//      "v" operands forces 28 VGPRs live at that point -> register allocator
//      must batch the 28 global loads (R8: VGPR=32, serial load->wait->use,
//      ~28 exposed VMEM latencies per V-pass; sched_barrier(0) didn't bind RA).
//  (2) XOR-swizzle stats LDS (byte ^= ((byte>>7)&7)<<4): H-phase b128 reads at
//      32B/lane stride were 4-way bank conflicts (5.5M cycles); swizzle makes
//      slot index 2L^(L>>2) within 16-lane groups -> 2-way (free). Same
//      transform on the 8B writes stays <=2-way; bijective.
// Keeps R8's XCD-bijective swizzle (FETCH 385->98 MB), 320-thread single-pass
// V-phase, uniform clamp+mask border path.

typedef float f32x2 __attribute__((ext_vector_type(2)));

#define IH 512
#define IW 512
#define TH 4                 // output rows per tile
#define TW 256               // output cols per tile
#define PW 266               // TW + 10 FIR cols
#define RRN 14               // raw rows per tile
#define LPW 268              // stats row stride in f32x2
#define HTILES 128
#define NTILE 24576          // 96 images * 128 ht * 2 wt
#define CPX 3072             // NTILE / 8 XCDs (exact -> bijective)
#define NBINS 64
#define NPIX 25165824.0f     // 96*512*512
#define NTHR 320

// LDS bank swizzle: XOR byte bits 4-6 with bits 7-9 (bijective; preserves
// 16B-alignment classes down to bit 4, and 8B halves within a 16B slot).
#define SWZ(b) ((b) ^ ((((b) >> 7) & 7) << 4))

constexpr float GW[11] = {
    0.00102838f, 0.00759877f, 0.03600078f, 0.10936070f, 0.21300554f,
    0.26601173f,
    0.21300554f, 0.10936070f, 0.03600078f, 0.00759877f, 0.00102838f
};
constexpr float C1f = 0.0001f;  // 0.01^2
constexpr float C2f = 0.0009f;  // 0.03^2

__global__ void ssim_zero(float* ws) { ws[threadIdx.x] = 0.0f; }

__global__ void ssim_fin(const float* __restrict__ ws, float* __restrict__ out) {
    float v = ws[threadIdx.x];
    #pragma unroll
    for (int off = 32; off > 0; off >>= 1) v += __shfl_down(v, off, 64);
    if (threadIdx.x == 0) out[0] = 1.0f - v * (1.0f / NPIX);
}

__global__ __launch_bounds__(NTHR, 2) void ssim_main(
    const float* __restrict__ pred,
    const float* __restrict__ targ,
    float* __restrict__ ws)
{
    __shared__ __align__(16) float sm01[TH * LPW * 2];   // (E[p], E[t]) swizzled
    __shared__ __align__(16) float sm23[TH * LPW * 2];   // (E[pp+tt], E[pt]) swizzled
    __shared__ float wsum[5];

    const int tid = threadIdx.x;

    // -------- XCD-aware bijective swizzle: tl-consecutive = same XCD -------
    const int b  = blockIdx.x;
    const int tl = (b & 7) * CPX + (b >> 3);     // tile-linear
    const int ht = tl & (HTILES - 1);            // consecutive ht share rows
    const int wt = (tl >> 7) & 1;
    const int bc = tl >> 8;

    const int rbase = ht * TH - 5;
    const float* __restrict__ P = pred + (size_t)bc * (IH * IW);
    const float* __restrict__ T = targ + (size_t)bc * (IH * IW);

    // ---------------- V-phase: batched loads + vertical FIR ----------------
    if (tid < PW) {
        const int w = wt * TW - 5 + tid;
        const float wm = ((unsigned)w < (unsigned)IW) ? 1.0f : 0.0f;
        const int wc = w < 0 ? 0 : (w > IW - 1 ? IW - 1 : w);

        // row masks + clamped 32-bit element offsets
        float rm[RRN];
        int off[RRN];
        #pragma unroll
        for (int rr = 0; rr < RRN; ++rr) {
            const int h = rbase + rr;
            rm[rr] = ((unsigned)h < (unsigned)IH) ? 1.0f : 0.0f;
            const int hc = h < 0 ? 0 : (h > IH - 1 ? IH - 1 : h);
            off[rr] = hc * IW + wc;
        }

        // batched loads -> registers; the asm anchor requires all 28 values
        // live in VGPRs simultaneously -> loads must batch, one vmcnt wait.
        float pv[RRN], tv[RRN];
        #pragma unroll
        for (int rr = 0; rr < RRN; ++rr) pv[rr] = P[off[rr]];
        #pragma unroll
        for (int rr = 0; rr < RRN; ++rr) tv[rr] = T[off[rr]];
        asm volatile("" ::
            "v"(pv[0]), "v"(pv[1]), "v"(pv[2]), "v"(pv[3]), "v"(pv[4]),
            "v"(pv[5]), "v"(pv[6]), "v"(pv[7]), "v"(pv[8]), "v"(pv[9]),
            "v"(pv[10]), "v"(pv[11]), "v"(pv[12]), "v"(pv[13]),
            "v"(tv[0]), "v"(tv[1]), "v"(tv[2]), "v"(tv[3]), "v"(tv[4]),
            "v"(tv[5]), "v"(tv[6]), "v"(tv[7]), "v"(tv[8]), "v"(tv[9]),
            "v"(tv[10]), "v"(tv[11]), "v"(tv[12]), "v"(tv[13]));

        f32x2 a01[TH], a23[TH];
        #pragma unroll
        for (int ro = 0; ro < TH; ++ro) {
            a01[ro].x = 0.f; a01[ro].y = 0.f;
            a23[ro].x = 0.f; a23[ro].y = 0.f;
        }

        #pragma unroll
        for (int rr = 0; rr < RRN; ++rr) {
            f32x2 s01; s01.x = pv[rr]; s01.y = tv[rr];
            const f32x2 rmv = {rm[rr], rm[rr]};
            s01 = s01 * rmv;                                  // border mask
            f32x2 s23;
            s23.x = fmaf(s01.x, s01.x, s01.y * s01.y);        // p^2 + t^2
            s23.y = s01.x * s01.y;                            // p*t
            #pragma unroll
            for (int ro = 0; ro < TH; ++ro) {
                const int k = rr - ro;       // compile-time after unroll
                if (k >= 0 && k < 11) {
                    const f32x2 g = {GW[k], GW[k]};
                    a01[ro] = __builtin_elementwise_fma(g, s01, a01[ro]);
                    a23[ro] = __builtin_elementwise_fma(g, s23, a23[ro]);
                }
            }
        }
        const f32x2 wmv = {wm, wm};
        char* const c01 = reinterpret_cast<char*>(sm01);
        char* const c23 = reinterpret_cast<char*>(sm23);
        #pragma unroll
        for (int ro = 0; ro < TH; ++ro) {
            const int wb = (ro * LPW + tid) * 8;
            *reinterpret_cast<f32x2*>(c01 + SWZ(wb)) = a01[ro] * wmv;
            *reinterpret_cast<f32x2*>(c23 + SWZ(wb)) = a23[ro] * wmv;
        }
    }
    __syncthreads();

    // ---------------- H-phase: horizontal conv + SSIM epilogue -------------
    float lsum = 0.0f;
    if (tid < 256) {
        const int r  = tid >> 6;            // 0..3
        const int c0 = (tid & 63) << 2;     // f32x2 element index, 0..252

        float4 u4[7], v4[7];
        const char* const c01 = reinterpret_cast<const char*>(sm01);
        const char* const c23 = reinterpret_cast<const char*>(sm23);
        #pragma unroll
        for (int q = 0; q < 7; ++q) {
            const int rb = (r * LPW + c0) * 8 + q * 16;
            u4[q] = *reinterpret_cast<const float4*>(c01 + SWZ(rb));
            v4[q] = *reinterpret_cast<const float4*>(c23 + SWZ(rb));
        }
        const f32x2* x01 = reinterpret_cast<const f32x2*>(u4);   // 14 elems
        const f32x2* x23 = reinterpret_cast<const f32x2*>(v4);

        #pragma unroll
        for (int j = 0; j < 4; ++j) {
            f32x2 acc01; acc01.x = 0.f; acc01.y = 0.f;
            f32x2 acc23; acc23.x = 0.f; acc23.y = 0.f;
            #pragma unroll
            for (int k = 0; k < 11; ++k) {
                const f32x2 g = {GW[k], GW[k]};
                acc01 = __builtin_elementwise_fma(g, x01[j + k], acc01);
                acc23 = __builtin_elementwise_fma(g, x23[j + k], acc23);
            }
            const float m1  = acc01.x;
            const float m2  = acc01.y;
            const float sPP = acc23.x;      // E[p^2]+E[t^2]
            const float e12 = acc23.y;      // E[p*t]
            const float m1m2 = m1 * m2;
            const float msq  = fmaf(m1, m1, m2 * m2);
            const float num = fmaf(2.0f, m1m2, C1f) * fmaf(2.0f, (e12 - m1m2), C2f);
            const float den = (msq + C1f) * ((sPP - msq) + C2f);
            lsum = fmaf(num, __builtin_amdgcn_rcpf(den), lsum);
        }
    }

    // ---------------- Reduction: wave shuffle -> LDS -> binned atomic ------
    #pragma unroll
    for (int off = 32; off > 0; off >>= 1) lsum += __shfl_down(lsum, off, 64);
    const int lane = tid & 63;
    const int wv   = tid >> 6;              // 0..4
    if (lane == 0) wsum[wv] = lsum;
    __syncthreads();
    if (tid == 0) {
        const float bs = wsum[0] + wsum[1] + wsum[2] + wsum[3] + wsum[4];
        atomicAdd(&ws[b & (NBINS - 1)], bs);
    }
}

extern "C" void kernel_launch(void* const* d_in, const int* in_sizes, int n_in,
                              void* d_out, int out_size, void* d_ws, size_t ws_size,
                              hipStream_t stream) {
    const float* pred = (const float*)d_in[0];
    const float* targ = (const float*)d_in[1];
    float* out = (float*)d_out;
    float* wsf = (float*)d_ws;

    hipLaunchKernelGGL(ssim_zero, dim3(1), dim3(NBINS), 0, stream, wsf);
    hipLaunchKernelGGL(ssim_main, dim3(NTILE), dim3(NTHR), 0, stream, pred, targ, wsf);
    hipLaunchKernelGGL(ssim_fin, dim3(1), dim3(64), 0, stream, wsf, out);
}

// Round 10
// 169.472 us; speedup vs baseline: 1.0024x; 1.0024x over previous
//
#include <hip/hip_runtime.h>

// SSIM loss, fused separable Gaussian (11x11, sigma=1.5) over [32,3,512,512] f32.
// R10 = R8 (linear stats LDS, XCD-bijective block swizzle, 320-thread single
// pass V-phase, clamp+mask borders) + FORCED batched V-phase loads:
//   28 inline-asm global_load_dword (SGPR base + 32b voffset). Volatile asms
//   preserve program order -> back-to-back issue; 28 distinct "=v" outputs all
//   live before one s_waitcnt vmcnt(0) -> RA must allocate 28 regs (compiler
//   refused at source level through R9: VGPR=32, one-at-a-time load->use,
//   ~4k cyc exposed latency per tile = the R2-R9 wall). sched_barrier(0)
//   after the waitcnt per guide rule #18.

typedef float f32x2 __attribute__((ext_vector_type(2)));
typedef unsigned int u32;

#define IH 512
#define IW 512
#define TH 4                 // output rows per tile
#define TW 256               // output cols per tile
#define PW 266               // TW + 10 FIR cols
#define RRN 14               // raw rows per tile
#define LPW 268              // stats row stride in f32x2
#define HTILES 128
#define NTILE 24576          // 96 images * 128 ht * 2 wt
#define CPX 3072             // NTILE / 8 XCDs (exact -> bijective)
#define NBINS 64
#define NPIX 25165824.0f     // 96*512*512
#define NTHR 320

constexpr float GW[11] = {
    0.00102838f, 0.00759877f, 0.03600078f, 0.10936070f, 0.21300554f,
    0.26601173f,
    0.21300554f, 0.10936070f, 0.03600078f, 0.00759877f, 0.00102838f
};
constexpr float C1f = 0.0001f;  // 0.01^2
constexpr float C2f = 0.0009f;  // 0.03^2

__global__ void ssim_zero(float* ws) { ws[threadIdx.x] = 0.0f; }

__global__ void ssim_fin(const float* __restrict__ ws, float* __restrict__ out) {
    float v = ws[threadIdx.x];
    #pragma unroll
    for (int off = 32; off > 0; off >>= 1) v += __shfl_down(v, off, 64);
    if (threadIdx.x == 0) out[0] = 1.0f - v * (1.0f / NPIX);
}

__global__ __launch_bounds__(NTHR, 2) void ssim_main(
    const float* __restrict__ pred,
    const float* __restrict__ targ,
    float* __restrict__ ws)
{
    __shared__ __align__(16) f32x2 lds01[TH][LPW];   // (E[p], E[t])
    __shared__ __align__(16) f32x2 lds23[TH][LPW];   // (E[p^2+t^2], E[p*t])
    __shared__ float wsum[5];

    const int tid = threadIdx.x;

    // -------- XCD-aware bijective swizzle: tl-consecutive = same XCD -------
    const int b  = blockIdx.x;
    const int tl = (b & 7) * CPX + (b >> 3);     // tile-linear
    const int ht = tl & (HTILES - 1);            // consecutive ht share rows
    const int wt = (tl >> 7) & 1;
    const int bc = tl >> 8;

    const int rbase = ht * TH - 5;
    const float* __restrict__ P = pred + (size_t)bc * (IH * IW);
    const float* __restrict__ T = targ + (size_t)bc * (IH * IW);

    // ---------------- V-phase: forced-batch loads + vertical FIR -----------
    if (tid < PW) {
        const int w = wt * TW - 5 + tid;
        const float wm = ((unsigned)w < (unsigned)IW) ? 1.0f : 0.0f;
        const int wc = w < 0 ? 0 : (w > IW - 1 ? IW - 1 : w);

        // row masks + clamped byte voffsets (SGPR-base + u32 voffset form)
        float rm[RRN];
        u32 voff[RRN];
        #pragma unroll
        for (int rr = 0; rr < RRN; ++rr) {
            const int h = rbase + rr;
            rm[rr] = ((unsigned)h < (unsigned)IH) ? 1.0f : 0.0f;
            const int hc = h < 0 ? 0 : (h > IH - 1 ? IH - 1 : h);
            voff[rr] = (u32)((hc * IW + wc) * 4);
        }

        // 28 volatile asm loads: program-ordered back-to-back issue, 28
        // distinct dest VGPRs live until the single vmcnt(0) drain.
        float pv[RRN], tv[RRN];
        #pragma unroll
        for (int rr = 0; rr < RRN; ++rr)
            asm volatile("global_load_dword %0, %1, %2"
                         : "=v"(pv[rr]) : "v"(voff[rr]), "s"(P));
        #pragma unroll
        for (int rr = 0; rr < RRN; ++rr)
            asm volatile("global_load_dword %0, %1, %2"
                         : "=v"(tv[rr]) : "v"(voff[rr]), "s"(T));
        asm volatile("s_waitcnt vmcnt(0)" ::: "memory");
        __builtin_amdgcn_sched_barrier(0);

        f32x2 a01[TH], a23[TH];
        #pragma unroll
        for (int ro = 0; ro < TH; ++ro) {
            a01[ro].x = 0.f; a01[ro].y = 0.f;
            a23[ro].x = 0.f; a23[ro].y = 0.f;
        }

        #pragma unroll
        for (int rr = 0; rr < RRN; ++rr) {
            f32x2 s01; s01.x = pv[rr]; s01.y = tv[rr];
            const f32x2 rmv = {rm[rr], rm[rr]};
            s01 = s01 * rmv;                                  // border mask
            f32x2 s23;
            s23.x = fmaf(s01.x, s01.x, s01.y * s01.y);        // p^2 + t^2
            s23.y = s01.x * s01.y;                            // p*t
            #pragma unroll
            for (int ro = 0; ro < TH; ++ro) {
                const int k = rr - ro;       // compile-time after unroll
                if (k >= 0 && k < 11) {
                    const f32x2 g = {GW[k], GW[k]};
                    a01[ro] = __builtin_elementwise_fma(g, s01, a01[ro]);
                    a23[ro] = __builtin_elementwise_fma(g, s23, a23[ro]);
                }
            }
        }
        const f32x2 wmv = {wm, wm};
        #pragma unroll
        for (int ro = 0; ro < TH; ++ro) {
            lds01[ro][tid] = a01[ro] * wmv;
            lds23[ro][tid] = a23[ro] * wmv;
        }
    }
    __syncthreads();

    // ---------------- H-phase: horizontal conv + SSIM epilogue -------------
    float lsum = 0.0f;
    if (tid < 256) {
        const int r  = tid >> 6;            // 0..3
        const int c0 = (tid & 63) << 2;     // 0..252

        float4 u4[7], v4[7];
        const float4* b01 = reinterpret_cast<const float4*>(&lds01[r][c0]);
        const float4* b23 = reinterpret_cast<const float4*>(&lds23[r][c0]);
        #pragma unroll
        for (int q = 0; q < 7; ++q) { u4[q] = b01[q]; v4[q] = b23[q]; }
        const f32x2* x01 = reinterpret_cast<const f32x2*>(u4);   // 14 elems
        const f32x2* x23 = reinterpret_cast<const f32x2*>(v4);

        #pragma unroll
        for (int j = 0; j < 4; ++j) {
            f32x2 acc01; acc01.x = 0.f; acc01.y = 0.f;
            f32x2 acc23; acc23.x = 0.f; acc23.y = 0.f;
            #pragma unroll
            for (int k = 0; k < 11; ++k) {
                const f32x2 g = {GW[k], GW[k]};
                acc01 = __builtin_elementwise_fma(g, x01[j + k], acc01);
                acc23 = __builtin_elementwise_fma(g, x23[j + k], acc23);
            }
            const float m1  = acc01.x;
            const float m2  = acc01.y;
            const float sPP = acc23.x;      // E[p^2]+E[t^2]
            const float e12 = acc23.y;      // E[p*t]
            const float m1m2 = m1 * m2;
            const float msq  = fmaf(m1, m1, m2 * m2);
            const float num = fmaf(2.0f, m1m2, C1f) * fmaf(2.0f, (e12 - m1m2), C2f);
            const float den = (msq + C1f) * ((sPP - msq) + C2f);
            lsum = fmaf(num, __builtin_amdgcn_rcpf(den), lsum);
        }
    }

    // ---------------- Reduction: wave shuffle -> LDS -> binned atomic ------
    #pragma unroll
    for (int off = 32; off > 0; off >>= 1) lsum += __shfl_down(lsum, off, 64);
    const int lane = tid & 63;
    const int wv   = tid >> 6;              // 0..4
    if (lane == 0) wsum[wv] = lsum;
    __syncthreads();
    if (tid == 0) {
        const float bs = wsum[0] + wsum[1] + wsum[2] + wsum[3] + wsum[4];
        atomicAdd(&ws[b & (NBINS - 1)], bs);
    }
}

extern "C" void kernel_launch(void* const* d_in, const int* in_sizes, int n_in,
                              void* d_out, int out_size, void* d_ws, size_t ws_size,
                              hipStream_t stream) {
    const float* pred = (const float*)d_in[0];
    const float* targ = (const float*)d_in[1];
    float* out = (float*)d_out;
    float* wsf = (float*)d_ws;

    hipLaunchKernelGGL(ssim_zero, dim3(1), dim3(NBINS), 0, stream, wsf);
    hipLaunchKernelGGL(ssim_main, dim3(NTILE), dim3(NTHR), 0, stream, pred, targ, wsf);
    hipLaunchKernelGGL(ssim_fin, dim3(1), dim3(64), 0, stream, wsf, out);
}

// Round 11
// 89.027 us; speedup vs baseline: 1.9083x; 1.9036x over previous
//
#include <hip/hip_runtime.h>

// SSIM loss, fused separable Gaussian (11x11, sigma=1.5) over [32,3,512,512] f32.
// R11 = R10 with the block-result ATOMICS REMOVED (single-variable change).
//   Diagnosis: dur was pinned 164-176 us across R2-R10 (VALU 2x varied, FETCH
//   4x varied) = 24576 blocks x ~7 ns -- the per-block device-scope f32
//   atomicAdd serializing at the coherence point. 64 bins = 4 cache lines
//   didn't parallelize it (cross-XCD line ping-pong).
//   Fix: block b plain-stores its partial to ws[b] (unique addr, no RMW);
//   a 1-block reduce kernel sums 24576 floats and writes 1 - sum/N.
// Kept from R10: XCD-bijective block swizzle (FETCH 385->98 MB), 320-thread
// single-pass V-phase, forced-batch asm loads, linear stats LDS, clamp+mask.

typedef float f32x2 __attribute__((ext_vector_type(2)));
typedef unsigned int u32;

#define IH 512
#define IW 512
#define TH 4                 // output rows per tile
#define TW 256               // output cols per tile
#define PW 266               // TW + 10 FIR cols
#define RRN 14               // raw rows per tile
#define LPW 268              // stats row stride in f32x2
#define HTILES 128
#define NTILE 24576          // 96 images * 128 ht * 2 wt
#define CPX 3072             // NTILE / 8 XCDs (exact -> bijective)
#define NPIX 25165824.0f     // 96*512*512
#define NTHR 320

constexpr float GW[11] = {
    0.00102838f, 0.00759877f, 0.03600078f, 0.10936070f, 0.21300554f,
    0.26601173f,
    0.21300554f, 0.10936070f, 0.03600078f, 0.00759877f, 0.00102838f
};
constexpr float C1f = 0.0001f;  // 0.01^2
constexpr float C2f = 0.0009f;  // 0.03^2

// Sum 24576 per-block partials -> out[0] = 1 - sum/NPIX. One block.
__global__ __launch_bounds__(1024) void ssim_reduce(
    const float* __restrict__ ws, float* __restrict__ out)
{
    __shared__ float wsum[16];
    const int tid = threadIdx.x;
    const float4* w4 = reinterpret_cast<const float4*>(ws);  // 6144 float4
    float s = 0.0f;
    #pragma unroll
    for (int i = 0; i < 6; ++i) {
        const float4 v = w4[tid + i * 1024];
        s += (v.x + v.y) + (v.z + v.w);
    }
    #pragma unroll
    for (int off = 32; off > 0; off >>= 1) s += __shfl_down(s, off, 64);
    if ((tid & 63) == 0) wsum[tid >> 6] = s;
    __syncthreads();
    if (tid == 0) {
        float t = 0.f;
        #pragma unroll
        for (int i = 0; i < 16; ++i) t += wsum[i];
        out[0] = 1.0f - t * (1.0f / NPIX);
    }
}

__global__ __launch_bounds__(NTHR, 2) void ssim_main(
    const float* __restrict__ pred,
    const float* __restrict__ targ,
    float* __restrict__ ws)
{
    __shared__ __align__(16) f32x2 lds01[TH][LPW];   // (E[p], E[t])
    __shared__ __align__(16) f32x2 lds23[TH][LPW];   // (E[p^2+t^2], E[p*t])
    __shared__ float wsum[5];

    const int tid = threadIdx.x;

    // -------- XCD-aware bijective swizzle: tl-consecutive = same XCD -------
    const int b  = blockIdx.x;
    const int tl = (b & 7) * CPX + (b >> 3);     // tile-linear
    const int ht = tl & (HTILES - 1);            // consecutive ht share rows
    const int wt = (tl >> 7) & 1;
    const int bc = tl >> 8;

    const int rbase = ht * TH - 5;
    const float* __restrict__ P = pred + (size_t)bc * (IH * IW);
    const float* __restrict__ T = targ + (size_t)bc * (IH * IW);

    // ---------------- V-phase: forced-batch loads + vertical FIR -----------
    if (tid < PW) {
        const int w = wt * TW - 5 + tid;
        const float wm = ((unsigned)w < (unsigned)IW) ? 1.0f : 0.0f;
        const int wc = w < 0 ? 0 : (w > IW - 1 ? IW - 1 : w);

        // row masks + clamped byte voffsets (SGPR-base + u32 voffset form)
        float rm[RRN];
        u32 voff[RRN];
        #pragma unroll
        for (int rr = 0; rr < RRN; ++rr) {
            const int h = rbase + rr;
            rm[rr] = ((unsigned)h < (unsigned)IH) ? 1.0f : 0.0f;
            const int hc = h < 0 ? 0 : (h > IH - 1 ? IH - 1 : h);
            voff[rr] = (u32)((hc * IW + wc) * 4);
        }

        // 28 volatile asm loads: program-ordered back-to-back issue, 28
        // distinct dest VGPRs live until the single vmcnt(0) drain.
        float pv[RRN], tv[RRN];
        #pragma unroll
        for (int rr = 0; rr < RRN; ++rr)
            asm volatile("global_load_dword %0, %1, %2"
                         : "=v"(pv[rr]) : "v"(voff[rr]), "s"(P));
        #pragma unroll
        for (int rr = 0; rr < RRN; ++rr)
            asm volatile("global_load_dword %0, %1, %2"
                         : "=v"(tv[rr]) : "v"(voff[rr]), "s"(T));
        asm volatile("s_waitcnt vmcnt(0)" ::: "memory");
        __builtin_amdgcn_sched_barrier(0);

        f32x2 a01[TH], a23[TH];
        #pragma unroll
        for (int ro = 0; ro < TH; ++ro) {
            a01[ro].x = 0.f; a01[ro].y = 0.f;
            a23[ro].x = 0.f; a23[ro].y = 0.f;
        }

        #pragma unroll
        for (int rr = 0; rr < RRN; ++rr) {
            f32x2 s01; s01.x = pv[rr]; s01.y = tv[rr];
            const f32x2 rmv = {rm[rr], rm[rr]};
            s01 = s01 * rmv;                                  // border mask
            f32x2 s23;
            s23.x = fmaf(s01.x, s01.x, s01.y * s01.y);        // p^2 + t^2
            s23.y = s01.x * s01.y;                            // p*t
            #pragma unroll
            for (int ro = 0; ro < TH; ++ro) {
                const int k = rr - ro;       // compile-time after unroll
                if (k >= 0 && k < 11) {
                    const f32x2 g = {GW[k], GW[k]};
                    a01[ro] = __builtin_elementwise_fma(g, s01, a01[ro]);
                    a23[ro] = __builtin_elementwise_fma(g, s23, a23[ro]);
                }
            }
        }
        const f32x2 wmv = {wm, wm};
        #pragma unroll
        for (int ro = 0; ro < TH; ++ro) {
            lds01[ro][tid] = a01[ro] * wmv;
            lds23[ro][tid] = a23[ro] * wmv;
        }
    }
    __syncthreads();

    // ---------------- H-phase: horizontal conv + SSIM epilogue -------------
    float lsum = 0.0f;
    if (tid < 256) {
        const int r  = tid >> 6;            // 0..3
        const int c0 = (tid & 63) << 2;     // 0..252

        float4 u4[7], v4[7];
        const float4* b01 = reinterpret_cast<const float4*>(&lds01[r][c0]);
        const float4* b23 = reinterpret_cast<const float4*>(&lds23[r][c0]);
        #pragma unroll
        for (int q = 0; q < 7; ++q) { u4[q] = b01[q]; v4[q] = b23[q]; }
        const f32x2* x01 = reinterpret_cast<const f32x2*>(u4);   // 14 elems
        const f32x2* x23 = reinterpret_cast<const f32x2*>(v4);

        #pragma unroll
        for (int j = 0; j < 4; ++j) {
            f32x2 acc01; acc01.x = 0.f; acc01.y = 0.f;
            f32x2 acc23; acc23.x = 0.f; acc23.y = 0.f;
            #pragma unroll
            for (int k = 0; k < 11; ++k) {
                const f32x2 g = {GW[k], GW[k]};
                acc01 = __builtin_elementwise_fma(g, x01[j + k], acc01);
                acc23 = __builtin_elementwise_fma(g, x23[j + k], acc23);
            }
            const float m1  = acc01.x;
            const float m2  = acc01.y;
            const float sPP = acc23.x;      // E[p^2]+E[t^2]
            const float e12 = acc23.y;      // E[p*t]
            const float m1m2 = m1 * m2;
            const float msq  = fmaf(m1, m1, m2 * m2);
            const float num = fmaf(2.0f, m1m2, C1f) * fmaf(2.0f, (e12 - m1m2), C2f);
            const float den = (msq + C1f) * ((sPP - msq) + C2f);
            lsum = fmaf(num, __builtin_amdgcn_rcpf(den), lsum);
        }
    }

    // ---------------- Reduction: wave shuffle -> LDS -> ONE PLAIN STORE ----
    #pragma unroll
    for (int off = 32; off > 0; off >>= 1) lsum += __shfl_down(lsum, off, 64);
    const int lane = tid & 63;
    const int wv   = tid >> 6;              // 0..4
    if (lane == 0) wsum[wv] = lsum;
    __syncthreads();
    if (tid == 0) {
        const float bs = wsum[0] + wsum[1] + wsum[2] + wsum[3] + wsum[4];
        ws[b] = bs;                          // unique address: no RMW, no
    }                                        // coherence-point serialization
}

extern "C" void kernel_launch(void* const* d_in, const int* in_sizes, int n_in,
                              void* d_out, int out_size, void* d_ws, size_t ws_size,
                              hipStream_t stream) {
    const float* pred = (const float*)d_in[0];
    const float* targ = (const float*)d_in[1];
    float* out = (float*)d_out;
    float* wsf = (float*)d_ws;               // needs 24576 floats = 96 KB

    hipLaunchKernelGGL(ssim_main, dim3(NTILE), dim3(NTHR), 0, stream,
                       pred, targ, wsf);
    hipLaunchKernelGGL(ssim_reduce, dim3(1), dim3(1024), 0, stream, wsf, out);
}